// Round 5
// baseline (348.941 us; speedup 1.0000x reference)
//
#include <hip/hip_runtime.h>
#include <hip/hip_bf16.h>

// B=2, S=2048, H=16, D=128, fp32 in/out, causal, interleaved RoPE.
// pass1 (pack_kv): rope(K), V^T as bf16 in lane-linear fragment-ordered
// 64x128 tiles (frag g at tile+g*1024B+lane*16B) in d_ws.
// pass2 (fattn5): flash attention; Q roped on the fly; K/V fragments read
// DIRECTLY from global (L2) as coalesced b128 loads -> no LDS staging, no
// __syncthreads at all; wave-private P round-trip in LDS; XCD-swizzled grid
// so all 16 q-blocks of one (b,h) share an XCD's L2.
#define B_  2
#define S_  2048
#define H_  16
#define D_  128
#define BQ  128
#define SH  (H_ * D_)        // 2048
#define NT  (S_ / 64)        // 32 key tiles (64 rows) per (b,h)
#define NTQ (S_ / BQ)        // 16 q-blocks per (b,h)
#define TILE_US 8192         // ushorts per 64x128 bf16 tile (16KB)

typedef __attribute__((ext_vector_type(8))) short bf16x8;
typedef __attribute__((ext_vector_type(4))) float f32x4;

__device__ __forceinline__ ushort f2bf(float x) {
  union { float f; unsigned u; } c; c.f = x;
  unsigned u = c.u;
  return (ushort)((u + 0x7FFFu + ((u >> 16) & 1u)) >> 16);
}

// ---------------------------------------------------------------------------
// Pass 1: pack rope(K) and V^T into lane-linear fragment tiles.
// K tile: frag g = (d>>5)*4 + (key>>4); within-frag lane = (key&15)|(((d>>3)&3)<<4)
// V^T tile: frag g = (key>>5)*8 + (d>>4); lane = (d&15)|(((key>>3)&3)<<4)
// ---------------------------------------------------------------------------
__global__ __launch_bounds__(256)
void pack_kv(const float* __restrict__ kg, const float* __restrict__ vg,
             const float* __restrict__ fg,
             ushort* __restrict__ kr, ushort* __restrict__ vt) {
  __shared__ float sv[64][133];
  const int t = blockIdx.x, h = blockIdx.y, b = blockIdx.z;
  const int tid = threadIdx.x;
  const size_t tbase = ((size_t)(b * H_ + h) * NT + t) * TILE_US;

  #pragma unroll
  for (int c = 0; c < 4; c++) {
    const int idx = tid + 256 * c;   // 0..1023
    const int row = idx >> 4;
    const int cu  = idx & 15;
    const int col = cu * 8;
    const int s   = t * 64 + row;
    const size_t goff = ((size_t)(b * S_ + s)) * SH + (size_t)h * D_ + col;

    const float4 f0 = *(const float4*)(fg + (size_t)s * D_ + col);
    const float4 f1 = *(const float4*)(fg + (size_t)s * D_ + col + 4);
    const float4 kx0 = *(const float4*)(kg + goff);
    const float4 kx1 = *(const float4*)(kg + goff + 4);
    const float4 vx0 = *(const float4*)(vg + goff);
    const float4 vx1 = *(const float4*)(vg + goff + 4);

    *(float4*)&sv[row][col]     = vx0;
    *(float4*)&sv[row][col + 4] = vx1;

    union { ushort s[8]; uint4 v; } pk;
    pk.s[0] = f2bf(f0.x*kx0.x - f0.y*kx0.y);
    pk.s[1] = f2bf(f0.y*kx0.x + f0.x*kx0.y);
    pk.s[2] = f2bf(f0.z*kx0.z - f0.w*kx0.w);
    pk.s[3] = f2bf(f0.w*kx0.z + f0.z*kx0.w);
    pk.s[4] = f2bf(f1.x*kx1.x - f1.y*kx1.y);
    pk.s[5] = f2bf(f1.y*kx1.x + f1.x*kx1.y);
    pk.s[6] = f2bf(f1.z*kx1.z - f1.w*kx1.w);
    pk.s[7] = f2bf(f1.w*kx1.z + f1.z*kx1.w);

    const int pos = ((cu >> 2) * 4 + (row >> 4)) * 64 + ((row & 15) | ((cu & 3) << 4));
    *(uint4*)(kr + tbase + (size_t)pos * 8) = pk.v;
  }
  __syncthreads();

  #pragma unroll
  for (int c = 0; c < 4; c++) {
    const int u2  = tid + 256 * c;     // = frag*64 + lane
    const int g2  = u2 >> 6;
    const int ln  = u2 & 63;
    const int dim = (g2 & 7) * 16 + (ln & 15);
    const int k0  = (g2 >> 3) * 32 + (ln >> 4) * 8;
    union { ushort s[8]; uint4 v; } p;
    #pragma unroll
    for (int j = 0; j < 8; j++) p.s[j] = f2bf(sv[k0 + j][dim]);
    *(uint4*)(vt + tbase + (size_t)u2 * 8) = p.v;
  }
}

// ---------------------------------------------------------------------------
// Pass 2: flash attention; K/V fragments direct from global; no barriers.
// ---------------------------------------------------------------------------
__global__ __launch_bounds__(256, 3)
void fattn5(const float* __restrict__ qg, const float* __restrict__ fg,
            const ushort* __restrict__ kr, const ushort* __restrict__ vt,
            float* __restrict__ og) {
  __shared__ __align__(16) ushort sP[4][2048];   // wave-private P (32x64 bf16)

  // linear-id swizzle: heavy qt first; same bh -> same id mod 8 -> same XCD.
  const int idx  = (int)blockIdx.x;
  const int qt   = NTQ - 1 - (idx >> 5);
  const int bh   = idx & 31;
  const int b    = bh >> 4;
  const int h    = bh & 15;
  const int tid  = threadIdx.x;
  const int wv   = tid >> 6;
  const int lane = tid & 63;
  const int l15  = lane & 15;
  const int quad = lane >> 4;

  const size_t bhs = (size_t)bh;
  const ushort* ktb = kr + bhs * NT * TILE_US;
  const ushort* vtb = vt + bhs * NT * TILE_US;
  const float QS = 0.08838834764831845f * 1.4426950408889634f; // 1/sqrt(128)*log2(e)

  // ---- Q fragments: RoPE on the fly (one-time per block) ----
  // afq[rh][ks]: lane holds Q[q=wv*32+rh*16+l15][d=ks*32+quad*8+(0..7)]*QS
  bf16x8 afq[2][4];
  {
    const float* qb = qg + ((size_t)b * S_ + (size_t)qt * BQ) * SH + (size_t)h * D_;
    #pragma unroll
    for (int rh = 0; rh < 2; rh++) {
      const int row = wv * 32 + rh * 16 + l15;
      const int s   = qt * BQ + row;
      #pragma unroll
      for (int ks = 0; ks < 4; ks++) {
        const int d0 = ks * 32 + quad * 8;
        const float4 x0 = *(const float4*)(qb + (size_t)row * SH + d0);
        const float4 x1 = *(const float4*)(qb + (size_t)row * SH + d0 + 4);
        const float4 f0 = *(const float4*)(fg + (size_t)s * D_ + d0);
        const float4 f1 = *(const float4*)(fg + (size_t)s * D_ + d0 + 4);
        union { ushort u[8]; bf16x8 v; } pq;
        pq.u[0] = f2bf((f0.x*x0.x - f0.y*x0.y) * QS);
        pq.u[1] = f2bf((f0.y*x0.x + f0.x*x0.y) * QS);
        pq.u[2] = f2bf((f0.z*x0.z - f0.w*x0.w) * QS);
        pq.u[3] = f2bf((f0.w*x0.z + f0.z*x0.w) * QS);
        pq.u[4] = f2bf((f1.x*x1.x - f1.y*x1.y) * QS);
        pq.u[5] = f2bf((f1.y*x1.x + f1.x*x1.y) * QS);
        pq.u[6] = f2bf((f1.z*x1.z - f1.w*x1.w) * QS);
        pq.u[7] = f2bf((f1.w*x1.z + f1.z*x1.w) * QS);
        afq[rh][ks] = pq.v;
      }
    }
  }

  float rs[2][4];
  f32x4 o_acc[2][8];
  #pragma unroll
  for (int rh = 0; rh < 2; rh++) {
    #pragma unroll
    for (int r = 0; r < 4; r++) rs[rh][r] = 0.0f;
    #pragma unroll
    for (int dt = 0; dt < 8; dt++) o_acc[rh][dt] = (f32x4)0.0f;
  }

  const int nkt = 2 * qt + 2;
  for (int kt = 0; kt < nkt; kt++) {
    const ushort* kp = ktb + (size_t)kt * TILE_US;
    const ushort* vp = vtb + (size_t)kt * TILE_US;

    // ---- S = Qs·K^T : K B-frags straight from global (coalesced b128) ----
    f32x4 sc[2][4];
    #pragma unroll
    for (int rh = 0; rh < 2; rh++)
      #pragma unroll
      for (int nt = 0; nt < 4; nt++) sc[rh][nt] = (f32x4)0.0f;
    #pragma unroll
    for (int nt = 0; nt < 4; nt++) {
      #pragma unroll
      for (int ks = 0; ks < 4; ks++) {
        const bf16x8 bk = *(const bf16x8*)(kp + (size_t)((ks * 4 + nt) * 64 + lane) * 8);
        sc[0][nt] = __builtin_amdgcn_mfma_f32_16x16x32_bf16(afq[0][ks], bk, sc[0][nt], 0, 0, 0);
        sc[1][nt] = __builtin_amdgcn_mfma_f32_16x16x32_bf16(afq[1][ks], bk, sc[1][nt], 0, 0, 0);
      }
    }

    // ---- causal mask (only last two tiles cross the diagonal) ----
    if (kt >= 2 * qt) {
      #pragma unroll
      for (int rh = 0; rh < 2; rh++) {
        #pragma unroll
        for (int nt = 0; nt < 4; nt++) {
          const int col = kt * 64 + nt * 16 + l15;
          #pragma unroll
          for (int r = 0; r < 4; r++) {
            const int row = qt * BQ + wv * 32 + rh * 16 + quad * 4 + r;
            if (col > row) sc[rh][nt][r] = -1e30f;
          }
        }
      }
    }

    // ---- max-free softmax + P pack into wave-private LDS ----
    #pragma unroll
    for (int rh = 0; rh < 2; rh++) {
      #pragma unroll
      for (int nt = 0; nt < 4; nt++) {
        const int base = rh * 1024 + (nt >> 1) * 512
                       + (((nt & 1) << 1) | (l15 >> 3)) * 128 + (l15 & 7);
        #pragma unroll
        for (int r = 0; r < 4; r++) {
          const float p = __builtin_amdgcn_exp2f(sc[rh][nt][r]);
          rs[rh][r] += p;
          sP[wv][base + (quad * 4 + r) * 8] = f2bf(p);
        }
      }
    }

    // ---- O += P·V : P A-frags from LDS, V B-frags straight from global ----
    bf16x8 ap[2][2];
    #pragma unroll
    for (int rh = 0; rh < 2; rh++)
      #pragma unroll
      for (int ks = 0; ks < 2; ks++)
        ap[rh][ks] = *(const bf16x8*)&sP[wv][(size_t)(rh * 1024 + (ks * 64 + lane) * 8)];
    #pragma unroll
    for (int dt = 0; dt < 8; dt++) {
      #pragma unroll
      for (int ks = 0; ks < 2; ks++) {
        const bf16x8 bv = *(const bf16x8*)(vp + (size_t)((ks * 8 + dt) * 64 + lane) * 8);
        o_acc[0][dt] = __builtin_amdgcn_mfma_f32_16x16x32_bf16(ap[0][ks], bv, o_acc[0][dt], 0, 0, 0);
        o_acc[1][dt] = __builtin_amdgcn_mfma_f32_16x16x32_bf16(ap[1][ks], bv, o_acc[1][dt], 0, 0, 0);
      }
    }
  }

  // ---- epilogue: deferred row-sum reduction, normalize, store ----
  float* ob = og + (bhs * S_ + (size_t)qt * BQ) * D_;
  #pragma unroll
  for (int rh = 0; rh < 2; rh++) {
    #pragma unroll
    for (int r = 0; r < 4; r++) {
      float t = rs[rh][r];
      t += __shfl_xor(t, 1);
      t += __shfl_xor(t, 2);
      t += __shfl_xor(t, 4);
      t += __shfl_xor(t, 8);
      const float inv = 1.0f / t;
      const int row = wv * 32 + rh * 16 + quad * 4 + r;
      #pragma unroll
      for (int dt = 0; dt < 8; dt++)
        ob[(size_t)row * D_ + dt * 16 + l15] = o_acc[rh][dt][r] * inv;
    }
  }
}

extern "C" void kernel_launch(void* const* d_in, const int* in_sizes, int n_in,
                              void* d_out, int out_size, void* d_ws, size_t ws_size,
                              hipStream_t stream) {
  const float* q = (const float*)d_in[0];
  const float* k = (const float*)d_in[1];
  const float* v = (const float*)d_in[2];
  const float* f = (const float*)d_in[3];
  float* o = (float*)d_out;

  const size_t NELT = (size_t)B_ * S_ * H_ * D_;   // 8388608
  ushort* kr = (ushort*)d_ws;
  ushort* vt = kr + NELT;

  dim3 block(256);
  pack_kv<<<dim3(NT, H_, B_), block, 0, stream>>>(k, v, f, kr, vt);
  fattn5<<<dim3(NTQ * 32, 1, 1), block, 0, stream>>>(q, f, kr, vt, o);
}

// Round 6
// 250.137 us; speedup vs baseline: 1.3950x; 1.3950x over previous
//
#include <hip/hip_runtime.h>
#include <hip/hip_bf16.h>

// B=2, S=2048, H=16, D=128, fp32 in/out, causal, interleaved RoPE.
// pass1 (pack_kv): rope(K), V^T as bf16 in lane-linear fragment-ordered
// 32-key x 128-dim tiles (8KB; frag g at tile+g*512B... g*64units+lane).
// pass2 (fattn6): SINGLE-WAVE blocks (64 thr), 64 q-rows/wave, BK=32,
// double-buffered global_load_lds staging (prefetch distance = 1 iter),
// no inter-wave barriers, max-free exp2 softmax, wave-private P round-trip.
#define B_  2
#define S_  2048
#define H_  16
#define D_  128
#define BQ  64               // q rows per (single-wave) block
#define BK  32               // keys per tile
#define SH  (H_ * D_)        // 2048
#define NT2 (S_ / BK)        // 64 key tiles per (b,h)
#define NTQ (S_ / BQ)        // 32 q-blocks per (b,h)
#define T2_US 4096           // ushorts per 32x128 bf16 tile (8KB)

typedef __attribute__((ext_vector_type(8))) short bf16x8;
typedef __attribute__((ext_vector_type(4))) float f32x4;

__device__ __forceinline__ ushort f2bf(float x) {   // RNE
  union { float f; unsigned u; } c; c.f = x;
  unsigned u = c.u;
  return (ushort)((u + 0x7FFFu + ((u >> 16) & 1u)) >> 16);
}
__device__ __forceinline__ ushort f2bf_fast(float x) {  // round-half-up (P only)
  union { float f; unsigned u; } c; c.f = x;
  return (ushort)((c.u + 0x8000u) >> 16);
}

// async global->LDS, 16B per lane; LDS dst = wave-uniform base + lane*16.
__device__ __forceinline__ void gload_lds16(const ushort* g, ushort* l) {
  __builtin_amdgcn_global_load_lds((const __attribute__((address_space(1))) void*)g,
                                   (__attribute__((address_space(3))) void*)l,
                                   16, 0, 0);
}

// ---------------------------------------------------------------------------
// Pass 1: pack rope(K) and V^T into lane-linear fragment tiles of 32 keys.
// K tile frag g = (dim>>5)*2 + (key>>4); in-frag lane = (key&15)|(((dim>>3)&3)<<4)
// V^T tile frag g = dim>>4;             in-frag lane = (dim&15)|(((key>>3)&3)<<4)
// Block packs 64 rows = 2 consecutive tiles.
// ---------------------------------------------------------------------------
__global__ __launch_bounds__(256)
void pack_kv(const float* __restrict__ kg, const float* __restrict__ vg,
             const float* __restrict__ fg,
             ushort* __restrict__ kr, ushort* __restrict__ vt) {
  __shared__ float sv[64][133];
  const int t = blockIdx.x, h = blockIdx.y, b = blockIdx.z;
  const int tid = threadIdx.x;
  const size_t tbase = ((size_t)(b * H_ + h) * NT2 + t * 2) * T2_US;

  #pragma unroll
  for (int c = 0; c < 4; c++) {
    const int idx = tid + 256 * c;   // 0..1023
    const int row = idx >> 4;        // 0..63
    const int cu  = idx & 15;
    const int col = cu * 8;
    const int s   = t * 64 + row;
    const size_t goff = ((size_t)(b * S_ + s)) * SH + (size_t)h * D_ + col;

    const float4 f0 = *(const float4*)(fg + (size_t)s * D_ + col);
    const float4 f1 = *(const float4*)(fg + (size_t)s * D_ + col + 4);
    const float4 kx0 = *(const float4*)(kg + goff);
    const float4 kx1 = *(const float4*)(kg + goff + 4);
    const float4 vx0 = *(const float4*)(vg + goff);
    const float4 vx1 = *(const float4*)(vg + goff + 4);

    *(float4*)&sv[row][col]     = vx0;
    *(float4*)&sv[row][col + 4] = vx1;

    union { ushort s[8]; uint4 v; } pk;
    pk.s[0] = f2bf(f0.x*kx0.x - f0.y*kx0.y);
    pk.s[1] = f2bf(f0.y*kx0.x + f0.x*kx0.y);
    pk.s[2] = f2bf(f0.z*kx0.z - f0.w*kx0.w);
    pk.s[3] = f2bf(f0.w*kx0.z + f0.z*kx0.w);
    pk.s[4] = f2bf(f1.x*kx1.x - f1.y*kx1.y);
    pk.s[5] = f2bf(f1.y*kx1.x + f1.x*kx1.y);
    pk.s[6] = f2bf(f1.z*kx1.z - f1.w*kx1.w);
    pk.s[7] = f2bf(f1.w*kx1.z + f1.z*kx1.w);

    const int t2  = row >> 5;
    const int r32 = row & 31;
    const int g   = (cu >> 2) * 2 + (r32 >> 4);
    const int ln  = (r32 & 15) | ((cu & 3) << 4);
    *(uint4*)(kr + tbase + (size_t)t2 * T2_US + (size_t)(g * 64 + ln) * 8) = pk.v;
  }
  __syncthreads();

  #pragma unroll
  for (int c = 0; c < 4; c++) {
    const int u2  = tid + 256 * c;     // 0..1023: t2(1) | g(3) | ln(6)
    const int t2  = u2 >> 9;
    const int g   = (u2 >> 6) & 7;
    const int ln  = u2 & 63;
    const int dim = g * 16 + (ln & 15);
    const int kl  = t2 * 32 + (ln >> 4) * 8;
    union { ushort s[8]; uint4 v; } p;
    #pragma unroll
    for (int j = 0; j < 8; j++) p.s[j] = f2bf(sv[kl + j][dim]);
    *(uint4*)(vt + tbase + (size_t)t2 * T2_US + (size_t)(g * 64 + ln) * 8) = p.v;
  }
}

// ---------------------------------------------------------------------------
// Pass 2: single-wave flash attention. 64 q-rows/wave, BK=32, dbuf staging.
// ---------------------------------------------------------------------------
__global__ __launch_bounds__(64, 1)
void fattn6(const float* __restrict__ qg, const float* __restrict__ fg,
            const ushort* __restrict__ kr, const ushort* __restrict__ vt,
            float* __restrict__ og) {
  __shared__ __align__(16) ushort sK[2][T2_US];   // 8KB x2
  __shared__ __align__(16) ushort sV[2][T2_US];   // 8KB x2
  __shared__ __align__(16) ushort sP[2048];       // 64x32 bf16 (4KB)

  // linear swizzle: heavy qt first; same bh -> same id mod 8 -> same XCD.
  const int idx  = (int)blockIdx.x;
  const int qt   = NTQ - 1 - (idx >> 5);
  const int bh   = idx & 31;
  const int b    = bh >> 4;
  const int h    = bh & 15;
  const int lane = threadIdx.x;
  const int l15  = lane & 15;
  const int quad = lane >> 4;

  const ushort* ktb = kr + (size_t)bh * NT2 * T2_US;
  const ushort* vtb = vt + (size_t)bh * NT2 * T2_US;
  const float QS = 0.08838834764831845f * 1.4426950408889634f; // 1/sqrt(128)*log2(e)

  // ---- Q fragments: RoPE on the fly. afq[rh][ks]: row=rh*16+l15, d=ks*32+quad*8+j
  bf16x8 afq[4][4];
  {
    const float* qb = qg + ((size_t)b * S_ + (size_t)qt * BQ) * SH + (size_t)h * D_;
    #pragma unroll
    for (int rh = 0; rh < 4; rh++) {
      const int row = rh * 16 + l15;
      const int s   = qt * BQ + row;
      #pragma unroll
      for (int ks = 0; ks < 4; ks++) {
        const int d0 = ks * 32 + quad * 8;
        const float4 x0 = *(const float4*)(qb + (size_t)row * SH + d0);
        const float4 x1 = *(const float4*)(qb + (size_t)row * SH + d0 + 4);
        const float4 f0 = *(const float4*)(fg + (size_t)s * D_ + d0);
        const float4 f1 = *(const float4*)(fg + (size_t)s * D_ + d0 + 4);
        union { ushort u[8]; bf16x8 v; } pq;
        pq.u[0] = f2bf((f0.x*x0.x - f0.y*x0.y) * QS);
        pq.u[1] = f2bf((f0.y*x0.x + f0.x*x0.y) * QS);
        pq.u[2] = f2bf((f0.z*x0.z - f0.w*x0.w) * QS);
        pq.u[3] = f2bf((f0.w*x0.z + f0.z*x0.w) * QS);
        pq.u[4] = f2bf((f1.x*x1.x - f1.y*x1.y) * QS);
        pq.u[5] = f2bf((f1.y*x1.x + f1.x*x1.y) * QS);
        pq.u[6] = f2bf((f1.z*x1.z - f1.w*x1.w) * QS);
        pq.u[7] = f2bf((f1.w*x1.z + f1.z*x1.w) * QS);
        afq[rh][ks] = pq.v;
      }
    }
  }

  float rs[4][4];
  f32x4 o_acc[4][8];
  #pragma unroll
  for (int rh = 0; rh < 4; rh++) {
    #pragma unroll
    for (int r = 0; r < 4; r++) rs[rh][r] = 0.0f;
    #pragma unroll
    for (int dt = 0; dt < 8; dt++) o_acc[rh][dt] = (f32x4)0.0f;
  }

  // prologue: stage tile 0 into buffer 0 (8 x 1KB per matrix)
  #pragma unroll
  for (int g = 0; g < 8; g++) {
    gload_lds16(ktb + (size_t)(g * 64 + lane) * 8, &sK[0][g * 512 + lane * 8]);
    gload_lds16(vtb + (size_t)(g * 64 + lane) * 8, &sV[0][g * 512 + lane * 8]);
  }

  const int nkt = 2 * qt + 2;
  int buf = 0;
  for (int kt = 0; kt < nkt; kt++) {
    __syncthreads();   // 1-wave: just drains vm/lgkm; tile kt ready in buf

    if (kt + 1 < nkt) {
      const ushort* kp = ktb + (size_t)(kt + 1) * T2_US;
      const ushort* vp = vtb + (size_t)(kt + 1) * T2_US;
      #pragma unroll
      for (int g = 0; g < 8; g++) {
        gload_lds16(kp + (size_t)(g * 64 + lane) * 8, &sK[buf ^ 1][g * 512 + lane * 8]);
        gload_lds16(vp + (size_t)(g * 64 + lane) * 8, &sV[buf ^ 1][g * 512 + lane * 8]);
      }
    }

    // ---- S = Qs·K^T : 64x32 per wave; 8 K-frag reads, 32 MFMAs ----
    f32x4 sc[4][2];
    #pragma unroll
    for (int rh = 0; rh < 4; rh++)
      #pragma unroll
      for (int nt = 0; nt < 2; nt++) sc[rh][nt] = (f32x4)0.0f;
    #pragma unroll
    for (int nt = 0; nt < 2; nt++) {
      #pragma unroll
      for (int ks = 0; ks < 4; ks++) {
        const bf16x8 bk = *(const bf16x8*)&sK[buf][(size_t)((ks * 2 + nt) * 64 + lane) * 8];
        #pragma unroll
        for (int rh = 0; rh < 4; rh++)
          sc[rh][nt] = __builtin_amdgcn_mfma_f32_16x16x32_bf16(afq[rh][ks], bk, sc[rh][nt], 0, 0, 0);
      }
    }

    // ---- causal mask (last two tiles) ----
    if (kt >= 2 * qt) {
      #pragma unroll
      for (int rh = 0; rh < 4; rh++) {
        #pragma unroll
        for (int nt = 0; nt < 2; nt++) {
          const int col = kt * BK + nt * 16 + l15;
          #pragma unroll
          for (int r = 0; r < 4; r++) {
            const int row = qt * BQ + rh * 16 + quad * 4 + r;
            if (col > row) sc[rh][nt][r] = -1e30f;
          }
        }
      }
    }

    // ---- max-free softmax + P pack ----
    #pragma unroll
    for (int rh = 0; rh < 4; rh++) {
      #pragma unroll
      for (int nt = 0; nt < 2; nt++) {
        const int base = rh * 512 + (nt * 2 + (l15 >> 3)) * 128 + (l15 & 7);
        #pragma unroll
        for (int r = 0; r < 4; r++) {
          const float p = __builtin_amdgcn_exp2f(sc[rh][nt][r]);
          rs[rh][r] += p;
          sP[base + (quad * 4 + r) * 8] = f2bf_fast(p);
        }
      }
    }

    // ---- O += P·V : 4 P-frag + 8 V-frag reads, 32 MFMAs ----
    bf16x8 ap[4];
    #pragma unroll
    for (int rh = 0; rh < 4; rh++)
      ap[rh] = *(const bf16x8*)&sP[(size_t)(rh * 512 + lane * 8)];
    #pragma unroll
    for (int dt = 0; dt < 8; dt++) {
      const bf16x8 bv = *(const bf16x8*)&sV[buf][(size_t)(dt * 64 + lane) * 8];
      #pragma unroll
      for (int rh = 0; rh < 4; rh++)
        o_acc[rh][dt] = __builtin_amdgcn_mfma_f32_16x16x32_bf16(ap[rh], bv, o_acc[rh][dt], 0, 0, 0);
    }

    buf ^= 1;
  }

  // ---- epilogue: deferred row-sum reduction, normalize, store ----
  float* ob = og + ((size_t)bh * S_ + (size_t)qt * BQ) * D_;
  #pragma unroll
  for (int rh = 0; rh < 4; rh++) {
    #pragma unroll
    for (int r = 0; r < 4; r++) {
      float t = rs[rh][r];
      t += __shfl_xor(t, 1);
      t += __shfl_xor(t, 2);
      t += __shfl_xor(t, 4);
      t += __shfl_xor(t, 8);
      const float inv = 1.0f / t;
      const int row = rh * 16 + quad * 4 + r;
      #pragma unroll
      for (int dt = 0; dt < 8; dt++)
        ob[(size_t)row * D_ + dt * 16 + l15] = o_acc[rh][dt][r] * inv;
    }
  }
}

extern "C" void kernel_launch(void* const* d_in, const int* in_sizes, int n_in,
                              void* d_out, int out_size, void* d_ws, size_t ws_size,
                              hipStream_t stream) {
  const float* q = (const float*)d_in[0];
  const float* k = (const float*)d_in[1];
  const float* v = (const float*)d_in[2];
  const float* f = (const float*)d_in[3];
  float* o = (float*)d_out;

  const size_t NELT = (size_t)B_ * S_ * H_ * D_;   // 8388608
  ushort* kr = (ushort*)d_ws;
  ushort* vt = kr + NELT;

  pack_kv<<<dim3(S_ / 64, H_, B_), dim3(256), 0, stream>>>(k, v, f, kr, vt);
  fattn6<<<dim3(NTQ * 32, 1, 1), dim3(64), 0, stream>>>(q, f, kr, vt, o);
}